// Round 1
// 2848.116 us; speedup vs baseline: 1.4209x; 1.4209x over previous
//
#include <hip/hip_runtime.h>
#include <math.h>

typedef __attribute__((ext_vector_type(8))) short bf16x8;   // 8 bf16 = 4 VGPR (MFMA A/B frag)
typedef __attribute__((ext_vector_type(4))) float f32x4;    // MFMA C/D frag

// ---------------- dtype helpers (runtime fp32-vs-bf16 sniff) ----------------

__device__ __forceinline__ float bf2f(unsigned short u) {
    union { unsigned int i; float f; } x; x.i = ((unsigned int)u) << 16; return x.f;
}
__device__ __forceinline__ unsigned short f2bf(float f) {
    union { float f; unsigned int i; } x; x.f = f;
    unsigned int i = x.i;
    unsigned int r = (i + 0x7FFFu + ((i >> 16) & 1u)) >> 16;   // RNE
    return (unsigned short)r;
}
__device__ __forceinline__ float ld1(const void* p, long i, bool bf) {
    return bf ? bf2f(((const unsigned short*)p)[i]) : ((const float*)p)[i];
}
__device__ __forceinline__ float4 ld4(const void* p, long i, bool bf) {
    if (bf) {
        ushort4 u = *(const ushort4*)((const unsigned short*)p + i);
        return make_float4(bf2f(u.x), bf2f(u.y), bf2f(u.z), bf2f(u.w));
    }
    return *(const float4*)((const float*)p + i);
}

// Detect whether float tensors are bf16-packed: look at low 16 bits of words of x
// (N(0,1) values). If bf16, bits[14:7] are an exponent near 127 (0x70..0x85
// almost always). If fp32, those are uniform mantissa bits (~8.6% hit rate).
__global__ void k_detect(const unsigned int* __restrict__ x, int* __restrict__ flag) {
    int t = threadIdx.x;
    int hits = 0;
    for (int i = 0; i < 64; i++) {
        unsigned int w = x[t * 64 + i];
        unsigned int e = (w >> 7) & 0xFF;
        hits += (e >= 0x70 && e <= 0x85) ? 1 : 0;
    }
    __shared__ int sh[256];
    sh[t] = hits;
    __syncthreads();
    for (int off = 128; off; off >>= 1) {
        if (t < off) sh[t] += sh[t + off];
        __syncthreads();
    }
    if (t == 0) *flag = (sh[0] > 8192) ? 1 : 0;   // 16384 words total
}

// ---------------- CSR build (counting sort by dst) ----------------

__global__ void k_hist(const int* __restrict__ dst, int E, int* __restrict__ counts) {
    int i = blockIdx.x * blockDim.x + threadIdx.x;
    if (i < E) atomicAdd(&counts[dst[i]], 1);
}

__global__ void k_scan_a(const int* __restrict__ counts, int N,
                         int* __restrict__ ex, int* __restrict__ bsums) {
    __shared__ int s[256];
    int t = threadIdx.x;
    int base = blockIdx.x * 1024;
    int v[4]; int sum = 0;
    #pragma unroll
    for (int j = 0; j < 4; j++) {
        int idx = base + t * 4 + j;
        v[j] = (idx < N) ? counts[idx] : 0;
        sum += v[j];
    }
    s[t] = sum;
    __syncthreads();
    for (int off = 1; off < 256; off <<= 1) {
        int x = (t >= off) ? s[t - off] : 0;
        __syncthreads();
        s[t] += x;
        __syncthreads();
    }
    int run = (t > 0) ? s[t - 1] : 0;
    #pragma unroll
    for (int j = 0; j < 4; j++) {
        int idx = base + t * 4 + j;
        if (idx < N) ex[idx] = run;
        run += v[j];
    }
    if (t == 255) bsums[blockIdx.x] = s[255];
}

__global__ void k_scan_b(int* __restrict__ bsums, int nb) {
    __shared__ int s[256];
    int t = threadIdx.x;
    s[t] = (t < nb) ? bsums[t] : 0;
    __syncthreads();
    for (int off = 1; off < 256; off <<= 1) {
        int x = (t >= off) ? s[t - off] : 0;
        __syncthreads();
        s[t] += x;
        __syncthreads();
    }
    if (t < nb) bsums[t] = (t > 0) ? s[t - 1] : 0;
}

__global__ void k_scan_c(const int* __restrict__ ex, const int* __restrict__ bsums,
                         int N, int E, int* __restrict__ row_ptr) {
    int i = blockIdx.x * blockDim.x + threadIdx.x;
    if (i < N) row_ptr[i] = ex[i] + bsums[i >> 10];
    if (i == 0) row_ptr[N] = E;
}

__global__ void k_scatter(const int* __restrict__ src, const int* __restrict__ dst,
                          const void* __restrict__ ewin, const int* __restrict__ dflag,
                          const int* __restrict__ row_ptr, int* __restrict__ cursor,
                          int E, int* __restrict__ es, float* __restrict__ ew) {
    int i = blockIdx.x * blockDim.x + threadIdx.x;
    if (i >= E) return;
    bool bf = (*dflag != 0);
    int d = dst[i];
    int p = row_ptr[d] + atomicAdd(&cursor[d], 1);
    es[p] = src[i];
    ew[p] = ld1(ewin, i, bf);
}

// ---------------- MFMA GEMM: C = act(A[M,K] @ W[K,N] (+ bias)) ----------------
// 128x128 tile, 256 threads (4 waves, 2x2), BK=32, mfma_f32_16x16x32_bf16.
// fp32 operands are split into bf16 hi+lo planes on the fly:
//   a*b ~= ah*bh + al*bh + ah*bl   (al*bl ~2^-18, dropped)
// bf16*bf16 products are exact in fp32; MFMA accumulates fp32 -> ~fp32 accuracy.
// Runtime skips: A direct-bf16 input -> no al pass; bf16 weights -> no bl pass.

__global__ __launch_bounds__(256) void k_gemm(
    const void* __restrict__ A, const void* __restrict__ W, const void* __restrict__ bias,
    float* __restrict__ C, int M, int K, int N,
    int a_is_input, int act, const int* __restrict__ dflag)
{
    const bool inbf = (*dflag != 0);
    const bool abf  = a_is_input && inbf;   // A already bf16: hi = raw bits, lo = 0
    const bool a_lo = !abf;
    const bool b_lo = !inbf;                // weights need lo only if inputs are fp32

    // [row][k] bf16, k contiguous; pad 32->40 elems (80 B) keeps 16B alignment
    // and makes the 16-row-strided ds_read_b128 ~2-way (free) instead of 16-way.
    __shared__ short Ah[128][40];
    __shared__ short Al[128][40];
    __shared__ short Bh[128][40];   // B stored transposed: [n][k]
    __shared__ short Bl[128][40];

    const int t  = threadIdx.x;
    const int m0 = blockIdx.y * 128;        // grid: x = n-tiles (fast) -> A-panel L2 reuse
    const int n0 = blockIdx.x * 128;

    const int lane = t & 63;
    const int wv   = t >> 6;
    const int wm   = (wv & 1) * 64;         // wave's 64x64 quadrant
    const int wn   = (wv >> 1) * 64;
    const int lr   = lane & 15;             // frag row/col
    const int lk   = (lane >> 4) * 8;       // frag k-offset (8 contiguous bf16 = b128)

    f32x4 acc[4][4];
    const f32x4 vzero = {0.f, 0.f, 0.f, 0.f};
    #pragma unroll
    for (int i = 0; i < 4; i++)
        #pragma unroll
        for (int j = 0; j < 4; j++) acc[i][j] = vzero;

    // A staging: thread -> (row = t>>1, k-half = (t&1)*16), 16 elems = 2x b128 per plane
    const int  ar  = t >> 1;
    const int  ak  = (t & 1) * 16;
    const long agm = (long)(m0 + ar);

    // B staging: thread -> (n-quad = t&31, k-quad-group = t>>5), transpose into LDS
    const int nq = t & 31;
    const int kq = t >> 5;
    const int gn = n0 + nq * 4;

    for (int k0 = 0; k0 < K; k0 += 32) {
        // ---- stage A tile (128 x 32) ----
        #pragma unroll
        for (int c = 0; c < 2; c++) {
            float4 v0 = make_float4(0.f, 0.f, 0.f, 0.f), v1 = v0;
            if (agm < M) {
                long base = agm * K + k0 + ak + c * 8;
                v0 = ld4(A, base, abf);
                v1 = ld4(A, base + 4, abf);
            }
            float f[8] = {v0.x, v0.y, v0.z, v0.w, v1.x, v1.y, v1.z, v1.w};
            union { unsigned short u[8]; uint4 q; } H, L;
            #pragma unroll
            for (int e = 0; e < 8; e++) {
                unsigned short h = f2bf(f[e]);
                H.u[e] = h;
                if (a_lo) L.u[e] = f2bf(f[e] - bf2f(h));
            }
            *(uint4*)&Ah[ar][ak + c * 8] = H.q;
            if (a_lo) *(uint4*)&Al[ar][ak + c * 8] = L.q;
        }
        // ---- stage B tile (32 x 128), transposed to [n][k] ----
        {
            float w[4][4];   // [k-off][n-off]
            #pragma unroll
            for (int i = 0; i < 4; i++) {
                float4 v = make_float4(0.f, 0.f, 0.f, 0.f);
                if (gn < N) v = ld4(W, (long)(k0 + kq * 4 + i) * N + gn, inbf);
                w[i][0] = v.x; w[i][1] = v.y; w[i][2] = v.z; w[i][3] = v.w;
            }
            #pragma unroll
            for (int j = 0; j < 4; j++) {
                union { unsigned short u[4]; uint2 q; } H, L;
                #pragma unroll
                for (int i = 0; i < 4; i++) {
                    unsigned short h = f2bf(w[i][j]);
                    H.u[i] = h;
                    if (b_lo) L.u[i] = f2bf(w[i][j] - bf2f(h));
                }
                *(uint2*)&Bh[nq * 4 + j][kq * 4] = H.q;
                if (b_lo) *(uint2*)&Bl[nq * 4 + j][kq * 4] = L.q;
            }
        }
        __syncthreads();

        // ---- MFMA: hi*hi (+ lo*hi) (+ hi*lo) ----
        bf16x8 ah[4], bh[4];
        #pragma unroll
        for (int f = 0; f < 4; f++) {
            ah[f] = *(const bf16x8*)&Ah[wm + f * 16 + lr][lk];
            bh[f] = *(const bf16x8*)&Bh[wn + f * 16 + lr][lk];
        }
        #pragma unroll
        for (int i = 0; i < 4; i++)
            #pragma unroll
            for (int j = 0; j < 4; j++)
                acc[i][j] = __builtin_amdgcn_mfma_f32_16x16x32_bf16(ah[i], bh[j], acc[i][j], 0, 0, 0);
        if (a_lo) {
            bf16x8 al[4];
            #pragma unroll
            for (int f = 0; f < 4; f++) al[f] = *(const bf16x8*)&Al[wm + f * 16 + lr][lk];
            #pragma unroll
            for (int i = 0; i < 4; i++)
                #pragma unroll
                for (int j = 0; j < 4; j++)
                    acc[i][j] = __builtin_amdgcn_mfma_f32_16x16x32_bf16(al[i], bh[j], acc[i][j], 0, 0, 0);
        }
        if (b_lo) {
            bf16x8 bl[4];
            #pragma unroll
            for (int f = 0; f < 4; f++) bl[f] = *(const bf16x8*)&Bl[wn + f * 16 + lr][lk];
            #pragma unroll
            for (int i = 0; i < 4; i++)
                #pragma unroll
                for (int j = 0; j < 4; j++)
                    acc[i][j] = __builtin_amdgcn_mfma_f32_16x16x32_bf16(ah[i], bl[j], acc[i][j], 0, 0, 0);
        }
        __syncthreads();
    }

    // ---- epilogue: C/D layout col=lane&15, row=(lane>>4)*4+reg [m89-verified] ----
    const bool has_bias = (bias != nullptr);
    const int  rbase = (lane >> 4) * 4;
    #pragma unroll
    for (int j = 0; j < 4; j++) {
        int col = n0 + wn + j * 16 + lr;
        if (col >= N) continue;
        float bv = has_bias ? ld1(bias, col, inbf) : 0.f;
        #pragma unroll
        for (int i = 0; i < 4; i++) {
            #pragma unroll
            for (int r = 0; r < 4; r++) {
                int row = m0 + wm + i * 16 + rbase + r;
                if (row < M) {
                    float v = acc[i][j][r] + bv;
                    if (act) v = fmaxf(v, 0.f);
                    C[(long)row * N + col] = v;
                }
            }
        }
    }
}

// ---------------- SPMM: out[d] = act(sum_e w[e]*sup[src[e]] + bias), F=256 ----------------
// one wave per dst node, lane l owns features [4l, 4l+4)

__global__ __launch_bounds__(256) void k_spmm(
    const float* __restrict__ sup, const int* __restrict__ es, const float* __restrict__ ew,
    const int* __restrict__ row_ptr, const void* __restrict__ bias,
    float* __restrict__ out, int Nn, int act, const int* __restrict__ dflag)
{
    const int wave = threadIdx.x >> 6;
    const int lane = threadIdx.x & 63;
    const int node = blockIdx.x * 4 + wave;
    if (node >= Nn) return;
    const bool bf = (*dflag != 0);

    const int e0 = row_ptr[node], e1 = row_ptr[node + 1];
    float4 acc = make_float4(0.f, 0.f, 0.f, 0.f);
    for (int e = e0; e < e1; e++) {
        int s = es[e];
        float w = ew[e];
        float4 v = *(const float4*)&sup[(long)s * 256 + lane * 4];
        acc.x += w * v.x; acc.y += w * v.y; acc.z += w * v.z; acc.w += w * v.w;
    }
    float4 b = ld4(bias, lane * 4, bf);
    acc.x += b.x; acc.y += b.y; acc.z += b.z; acc.w += b.w;
    if (act) {
        acc.x = fmaxf(acc.x, 0.f); acc.y = fmaxf(acc.y, 0.f);
        acc.z = fmaxf(acc.z, 0.f); acc.w = fmaxf(acc.w, 0.f);
    }
    *(float4*)&out[(long)node * 256 + lane * 4] = acc;
}

// ---------------- softmax over NC classes, one wave per row ----------------

__global__ __launch_bounds__(256) void k_softmax(
    const float* __restrict__ logits, void* __restrict__ out, int M, int NC,
    const int* __restrict__ dflag)
{
    const int wave = threadIdx.x >> 6;
    const int lane = threadIdx.x & 63;
    const int row = blockIdx.x * 4 + wave;
    if (row >= M) return;
    const bool bf = (*dflag != 0);

    float v = (lane < NC) ? logits[(long)row * NC + lane] : -INFINITY;
    float m = v;
    #pragma unroll
    for (int off = 32; off; off >>= 1) m = fmaxf(m, __shfl_xor(m, off, 64));
    float p = (lane < NC) ? expf(v - m) : 0.f;
    float s = p;
    #pragma unroll
    for (int off = 32; off; off >>= 1) s += __shfl_xor(s, off, 64);
    if (lane < NC) {
        float r = p / s;
        if (bf) ((unsigned short*)out)[(long)row * NC + lane] = f2bf(r);
        else    ((float*)out)[(long)row * NC + lane] = r;
    }
}

// ---------------- orchestration ----------------

extern "C" void kernel_launch(void* const* d_in, const int* in_sizes, int n_in,
                              void* d_out, int out_size, void* d_ws, size_t ws_size,
                              hipStream_t stream) {
    const void* x    = d_in[0];
    const int*  esrc = (const int*)d_in[1];
    const int*  edst = (const int*)d_in[2];
    const void* ewin = d_in[3];
    const void* w1 = d_in[4],  *b1 = d_in[5];
    const void* w2 = d_in[6],  *b2 = d_in[7];
    const void* wc1 = d_in[8], *bc1 = d_in[9];
    const void* wc2 = d_in[10], *bc2 = d_in[11];
    const void* wc3 = d_in[12], *bc3 = d_in[13];
    const void* wc4 = d_in[14], *bc4 = d_in[15];

    const int HID  = in_sizes[5];                 // 256
    const int IND  = in_sizes[4] / HID;           // 512
    const int HID2 = in_sizes[9];                 // 512
    const int NC   = in_sizes[15];                // 40
    const int M    = in_sizes[0] / IND;           // 100000
    const int E    = in_sizes[1];                 // 3200000

    char* ws = (char*)d_ws;
    int* dflag = (int*)ws;                                        // 256 B slot
    float* bufA = (float*)(ws + 256);                             // M*HID fp32 = 102.4 MB
    float* bufB = (float*)(ws + 256 + 102400000L);                // 102.4 MB
    char*  wsC  = ws + 256 + 204800000L;                          // 204.8 MB (h3/h5)
    char*  wsD  = wsC + 204800000L;                               // 204.8 MB (h4)
    float* bufC = (float*)wsC;
    float* bufD = (float*)wsD;

    // CSR arrays live inside bufC's region (dead before the MLP starts)
    int* counts  = (int*)wsC;
    int* row_ptr = counts + 100352;
    int* cursor  = row_ptr + 100352;
    int* bsums   = cursor + 100352;
    int* ex      = bsums + 1024;
    int* es      = ex + 100352;
    float* ewS   = (float*)(es + E);

    float* logits = bufA;   // reuse after support2 is dead (16 MB < 102.4 MB)

    // 0. dtype sniff
    k_detect<<<1, 256, 0, stream>>>((const unsigned int*)x, dflag);

    // 1. CSR build
    hipMemsetAsync(counts, 0, 100352 * sizeof(int), stream);
    hipMemsetAsync(cursor, 0, 100352 * sizeof(int), stream);
    k_hist<<<(E + 255) / 256, 256, 0, stream>>>(edst, E, counts);
    int nb = (M + 1023) / 1024;                                   // 98
    k_scan_a<<<nb, 256, 0, stream>>>(counts, M, ex, bsums);
    k_scan_b<<<1, 256, 0, stream>>>(bsums, nb);
    k_scan_c<<<(M + 255) / 256, 256, 0, stream>>>(ex, bsums, M, E, row_ptr);
    k_scatter<<<(E + 255) / 256, 256, 0, stream>>>(esrc, edst, ewin, dflag, row_ptr, cursor, E, es, ewS);

    const int gm128 = (M + 127) / 128;   // 782
    dim3 blk(256);

    // 2. support1 = x @ w1                      [M,512]@[512,256] -> bufA
    k_gemm<<<dim3(HID / 128, gm128), blk, 0, stream>>>(x, w1, nullptr, bufA, M, IND, HID, 1, 0, dflag);
    // 3. h1 = relu(spmm(support1) + b1)        -> bufB
    k_spmm<<<(M + 3) / 4, blk, 0, stream>>>(bufA, es, ewS, row_ptr, b1, bufB, M, 1, dflag);
    // 4. support2 = h1 @ w2                    -> bufA
    k_gemm<<<dim3(HID / 128, gm128), blk, 0, stream>>>(bufB, w2, nullptr, bufA, M, HID, HID, 0, 0, dflag);
    // 5. h2 = spmm(support2) + b2              -> bufB
    k_spmm<<<(M + 3) / 4, blk, 0, stream>>>(bufA, es, ewS, row_ptr, b2, bufB, M, 0, dflag);
    // 6. h3 = relu(h2 @ wc1 + bc1)             [M,256]@[256,512] -> bufC  (CSR now dead)
    k_gemm<<<dim3(HID2 / 128, gm128), blk, 0, stream>>>(bufB, wc1, bc1, bufC, M, HID, HID2, 0, 1, dflag);
    // 7. h4 = relu(h3 @ wc2 + bc2)             -> bufD
    k_gemm<<<dim3(HID2 / 128, gm128), blk, 0, stream>>>(bufC, wc2, bc2, bufD, M, HID2, HID2, 0, 1, dflag);
    // 8. h5 = relu(h4 @ wc3 + bc3)             -> bufC
    k_gemm<<<dim3(HID2 / 128, gm128), blk, 0, stream>>>(bufD, wc3, bc3, bufC, M, HID2, HID2, 0, 1, dflag);
    // 9. logits = h5 @ wc4 + bc4               [M,512]@[512,40] -> bufA
    k_gemm<<<dim3(1, gm128), blk, 0, stream>>>(bufC, wc4, bc4, logits, M, HID2, NC, 0, 0, dflag);
    // 10. softmax -> d_out
    k_softmax<<<(M + 3) / 4, blk, 0, stream>>>(logits, d_out, M, NC, dflag);
}

// Round 2
// 2402.417 us; speedup vs baseline: 1.6845x; 1.1855x over previous
//
#include <hip/hip_runtime.h>
#include <math.h>

typedef __attribute__((ext_vector_type(8))) short bf16x8;   // 8 bf16 = 4 VGPR (MFMA A/B frag)
typedef __attribute__((ext_vector_type(4))) float f32x4;    // MFMA C/D frag

// ---------------- dtype helpers ----------------

__device__ __forceinline__ float bf2f(unsigned short u) {
    union { unsigned int i; float f; } x; x.i = ((unsigned int)u) << 16; return x.f;
}
__device__ __forceinline__ unsigned short f2bf(float f) {
    union { float f; unsigned int i; } x; x.f = f;
    unsigned int i = x.i;
    unsigned int r = (i + 0x7FFFu + ((i >> 16) & 1u)) >> 16;   // RNE
    return (unsigned short)r;
}
__device__ __forceinline__ float h2f(unsigned short u) {
    _Float16 h; __builtin_memcpy(&h, &u, 2); return (float)h;
}
__device__ __forceinline__ unsigned short f2h(float f) {
    _Float16 h = (_Float16)f; unsigned short u; __builtin_memcpy(&u, &h, 2); return u;
}
__device__ __forceinline__ float ld1(const void* p, long i, bool bf) {
    return bf ? bf2f(((const unsigned short*)p)[i]) : ((const float*)p)[i];
}
__device__ __forceinline__ float4 ld4(const void* p, long i, bool bf) {
    if (bf) {
        ushort4 u = *(const ushort4*)((const unsigned short*)p + i);
        return make_float4(bf2f(u.x), bf2f(u.y), bf2f(u.z), bf2f(u.w));
    }
    return *(const float4*)((const float*)p + i);
}

// Detect whether float tensors are bf16-packed (see round 0 notes).
__global__ void k_detect(const unsigned int* __restrict__ x, int* __restrict__ flag) {
    int t = threadIdx.x;
    int hits = 0;
    for (int i = 0; i < 64; i++) {
        unsigned int w = x[t * 64 + i];
        unsigned int e = (w >> 7) & 0xFF;
        hits += (e >= 0x70 && e <= 0x85) ? 1 : 0;
    }
    __shared__ int sh[256];
    sh[t] = hits;
    __syncthreads();
    for (int off = 128; off; off >>= 1) {
        if (t < off) sh[t] += sh[t + off];
        __syncthreads();
    }
    if (t == 0) *flag = (sh[0] > 8192) ? 1 : 0;   // 16384 words total
}

// ---------------- CSR build (counting sort by dst) ----------------

__global__ void k_hist(const int* __restrict__ dst, int E, int* __restrict__ counts) {
    int i = blockIdx.x * blockDim.x + threadIdx.x;
    if (i < E) atomicAdd(&counts[dst[i]], 1);
}

__global__ void k_scan_a(const int* __restrict__ counts, int N,
                         int* __restrict__ ex, int* __restrict__ bsums) {
    __shared__ int s[256];
    int t = threadIdx.x;
    int base = blockIdx.x * 1024;
    int v[4]; int sum = 0;
    #pragma unroll
    for (int j = 0; j < 4; j++) {
        int idx = base + t * 4 + j;
        v[j] = (idx < N) ? counts[idx] : 0;
        sum += v[j];
    }
    s[t] = sum;
    __syncthreads();
    for (int off = 1; off < 256; off <<= 1) {
        int x = (t >= off) ? s[t - off] : 0;
        __syncthreads();
        s[t] += x;
        __syncthreads();
    }
    int run = (t > 0) ? s[t - 1] : 0;
    #pragma unroll
    for (int j = 0; j < 4; j++) {
        int idx = base + t * 4 + j;
        if (idx < N) ex[idx] = run;
        run += v[j];
    }
    if (t == 255) bsums[blockIdx.x] = s[255];
}

__global__ void k_scan_b(int* __restrict__ bsums, int nb) {
    __shared__ int s[256];
    int t = threadIdx.x;
    s[t] = (t < nb) ? bsums[t] : 0;
    __syncthreads();
    for (int off = 1; off < 256; off <<= 1) {
        int x = (t >= off) ? s[t - off] : 0;
        __syncthreads();
        s[t] += x;
        __syncthreads();
    }
    if (t < nb) bsums[t] = (t > 0) ? s[t - 1] : 0;
}

__global__ void k_scan_c(const int* __restrict__ ex, const int* __restrict__ bsums,
                         int N, int E, int* __restrict__ row_ptr) {
    int i = blockIdx.x * blockDim.x + threadIdx.x;
    if (i < N) row_ptr[i] = ex[i] + bsums[i >> 10];
    if (i == 0) row_ptr[N] = E;
}

__global__ void k_scatter(const int* __restrict__ src, const int* __restrict__ dst,
                          const void* __restrict__ ewin, const int* __restrict__ dflag,
                          const int* __restrict__ row_ptr, int* __restrict__ cursor,
                          int E, int* __restrict__ es, float* __restrict__ ew) {
    int i = blockIdx.x * blockDim.x + threadIdx.x;
    if (i >= E) return;
    bool bf = (*dflag != 0);
    int d = dst[i];
    int p = row_ptr[d] + atomicAdd(&cursor[d], 1);
    es[p] = src[i];
    ew[p] = ld1(ewin, i, bf);
}

// ---------------- MFMA GEMM: C = act(A[M,K] @ W[K,N] (+ bias)) ----------------
// 128x128 tile, 256 threads (4 waves, 2x2), BK=32, mfma_f32_16x16x32_bf16.
// A modes: a_kind=0 -> input tensor (fp32 or raw-bf16 per dflag)
//          a_kind=2 -> fp16 intermediate; EXACT hi/lo bf16 split
//              (11-bit f16 significand = 8-bit hi + <=3-bit lo, both exact in bf16)
// fp32 operands split on the fly: a*b ~= ah*bh + al*bh (+ ah*bl if fp32 weights).
// c_mode: 0 = fp32 store, 2 = fp16 store.

__global__ __launch_bounds__(256) void k_gemm(
    const void* __restrict__ A, const void* __restrict__ W, const void* __restrict__ bias,
    void* __restrict__ C, int M, int K, int N,
    int a_kind, int c_mode, int act, const int* __restrict__ dflag)
{
    const bool inbf = (*dflag != 0);
    const int  a_mode = (a_kind == 2) ? 2 : (inbf ? 1 : 0);   // 0 fp32, 1 bf16 raw, 2 f16
    const bool a_lo = (a_mode != 1);
    const bool b_lo = !inbf;

    // [row][k] bf16, k contiguous; pad 32->40 elems keeps 16B alignment and
    // makes the 16-row-strided ds_read_b128 ~2-way (free) instead of 16-way.
    __shared__ short Ah[128][40];
    __shared__ short Al[128][40];
    __shared__ short Bh[128][40];   // B stored transposed: [n][k]
    __shared__ short Bl[128][40];

    const int t  = threadIdx.x;
    const int m0 = blockIdx.y * 128;        // grid: x = n-tiles (fast) -> A-panel L2 reuse
    const int n0 = blockIdx.x * 128;

    const int lane = t & 63;
    const int wv   = t >> 6;
    const int wm   = (wv & 1) * 64;         // wave's 64x64 quadrant
    const int wn   = (wv >> 1) * 64;
    const int lr   = lane & 15;             // frag row/col
    const int lk   = (lane >> 4) * 8;       // frag k-offset (8 contiguous bf16 = b128)

    f32x4 acc[4][4];
    const f32x4 vzero = {0.f, 0.f, 0.f, 0.f};
    #pragma unroll
    for (int i = 0; i < 4; i++)
        #pragma unroll
        for (int j = 0; j < 4; j++) acc[i][j] = vzero;

    // A staging: thread -> (row = t>>1, k-half = (t&1)*16), 16 elems = 2x 8 per plane
    const int  ar  = t >> 1;
    const int  ak  = (t & 1) * 16;
    const long agm = (long)(m0 + ar);

    // B staging: thread -> (n-quad = t&31, k-quad-group = t>>5), transpose into LDS
    const int nq = t & 31;
    const int kq = t >> 5;
    const int gn = n0 + nq * 4;

    for (int k0 = 0; k0 < K; k0 += 32) {
        // ---- stage A tile (128 x 32) ----
        #pragma unroll
        for (int c = 0; c < 2; c++) {
            long base = agm * K + k0 + ak + c * 8;
            if (a_mode == 1) {
                uint4 raw = make_uint4(0, 0, 0, 0);
                if (agm < M) raw = *(const uint4*)((const unsigned short*)A + base);
                *(uint4*)&Ah[ar][ak + c * 8] = raw;
            } else {
                float f[8];
                if (a_mode == 0) {
                    float4 v0 = make_float4(0.f, 0.f, 0.f, 0.f), v1 = v0;
                    if (agm < M) {
                        v0 = *(const float4*)((const float*)A + base);
                        v1 = *(const float4*)((const float*)A + base + 4);
                    }
                    f[0]=v0.x; f[1]=v0.y; f[2]=v0.z; f[3]=v0.w;
                    f[4]=v1.x; f[5]=v1.y; f[6]=v1.z; f[7]=v1.w;
                } else {
                    union { unsigned short u[8]; uint4 q; } r;
                    r.q = make_uint4(0, 0, 0, 0);
                    if (agm < M) r.q = *(const uint4*)((const unsigned short*)A + base);
                    #pragma unroll
                    for (int e = 0; e < 8; e++) f[e] = h2f(r.u[e]);
                }
                union { unsigned short u[8]; uint4 q; } H, L;
                #pragma unroll
                for (int e = 0; e < 8; e++) {
                    unsigned short h = f2bf(f[e]);
                    H.u[e] = h;
                    L.u[e] = f2bf(f[e] - bf2f(h));
                }
                *(uint4*)&Ah[ar][ak + c * 8] = H.q;
                *(uint4*)&Al[ar][ak + c * 8] = L.q;
            }
        }
        // ---- stage B tile (32 x 128), transposed to [n][k] ----
        {
            float w[4][4];   // [k-off][n-off]
            #pragma unroll
            for (int i = 0; i < 4; i++) {
                float4 v = make_float4(0.f, 0.f, 0.f, 0.f);
                if (gn < N) v = ld4(W, (long)(k0 + kq * 4 + i) * N + gn, inbf);
                w[i][0] = v.x; w[i][1] = v.y; w[i][2] = v.z; w[i][3] = v.w;
            }
            #pragma unroll
            for (int j = 0; j < 4; j++) {
                union { unsigned short u[4]; uint2 q; } H, L;
                #pragma unroll
                for (int i = 0; i < 4; i++) {
                    unsigned short h = f2bf(w[i][j]);
                    H.u[i] = h;
                    if (b_lo) L.u[i] = f2bf(w[i][j] - bf2f(h));
                }
                *(uint2*)&Bh[nq * 4 + j][kq * 4] = H.q;
                if (b_lo) *(uint2*)&Bl[nq * 4 + j][kq * 4] = L.q;
            }
        }
        __syncthreads();

        // ---- MFMA: hi*hi (+ lo*hi) (+ hi*lo) ----
        bf16x8 ah[4], bh[4];
        #pragma unroll
        for (int f = 0; f < 4; f++) {
            ah[f] = *(const bf16x8*)&Ah[wm + f * 16 + lr][lk];
            bh[f] = *(const bf16x8*)&Bh[wn + f * 16 + lr][lk];
        }
        #pragma unroll
        for (int i = 0; i < 4; i++)
            #pragma unroll
            for (int j = 0; j < 4; j++)
                acc[i][j] = __builtin_amdgcn_mfma_f32_16x16x32_bf16(ah[i], bh[j], acc[i][j], 0, 0, 0);
        if (a_lo) {
            bf16x8 al[4];
            #pragma unroll
            for (int f = 0; f < 4; f++) al[f] = *(const bf16x8*)&Al[wm + f * 16 + lr][lk];
            #pragma unroll
            for (int i = 0; i < 4; i++)
                #pragma unroll
                for (int j = 0; j < 4; j++)
                    acc[i][j] = __builtin_amdgcn_mfma_f32_16x16x32_bf16(al[i], bh[j], acc[i][j], 0, 0, 0);
        }
        if (b_lo) {
            bf16x8 bl[4];
            #pragma unroll
            for (int f = 0; f < 4; f++) bl[f] = *(const bf16x8*)&Bl[wn + f * 16 + lr][lk];
            #pragma unroll
            for (int i = 0; i < 4; i++)
                #pragma unroll
                for (int j = 0; j < 4; j++)
                    acc[i][j] = __builtin_amdgcn_mfma_f32_16x16x32_bf16(ah[i], bl[j], acc[i][j], 0, 0, 0);
        }
        __syncthreads();
    }

    // ---- epilogue: C/D layout col=lane&15, row=(lane>>4)*4+reg [m89-verified] ----
    const bool has_bias = (bias != nullptr);
    const int  rbase = (lane >> 4) * 4;
    #pragma unroll
    for (int j = 0; j < 4; j++) {
        int col = n0 + wn + j * 16 + lr;
        if (col >= N) continue;
        float bv = has_bias ? ld1(bias, col, inbf) : 0.f;
        #pragma unroll
        for (int i = 0; i < 4; i++) {
            #pragma unroll
            for (int r = 0; r < 4; r++) {
                int row = m0 + wm + i * 16 + rbase + r;
                if (row < M) {
                    float v = acc[i][j][r] + bv;
                    if (act) v = fmaxf(v, 0.f);
                    if (c_mode == 2) ((unsigned short*)C)[(long)row * N + col] = f2h(v);
                    else             ((float*)C)[(long)row * N + col] = v;
                }
            }
        }
    }
}

// ---------------- SPMM: out[d] = act(sum_e w[e]*sup[src[e]] + bias), F=256 ----------------
// one wave per dst node, lane l owns features [4l, 4l+4). sup and out are fp16.

__global__ __launch_bounds__(256) void k_spmm(
    const unsigned short* __restrict__ sup, const int* __restrict__ es,
    const float* __restrict__ ew, const int* __restrict__ row_ptr,
    const void* __restrict__ bias, unsigned short* __restrict__ out,
    int Nn, int act, const int* __restrict__ dflag)
{
    const int wave = threadIdx.x >> 6;
    const int lane = threadIdx.x & 63;
    const int node = blockIdx.x * 4 + wave;
    if (node >= Nn) return;
    const bool bf = (*dflag != 0);

    const int e0 = row_ptr[node], e1 = row_ptr[node + 1];
    float4 acc = make_float4(0.f, 0.f, 0.f, 0.f);
    for (int e = e0; e < e1; e++) {
        int s = es[e];
        float w = ew[e];
        ushort4 u = *(const ushort4*)&sup[(long)s * 256 + lane * 4];
        acc.x += w * h2f(u.x); acc.y += w * h2f(u.y);
        acc.z += w * h2f(u.z); acc.w += w * h2f(u.w);
    }
    float4 b = ld4(bias, lane * 4, bf);
    acc.x += b.x; acc.y += b.y; acc.z += b.z; acc.w += b.w;
    if (act) {
        acc.x = fmaxf(acc.x, 0.f); acc.y = fmaxf(acc.y, 0.f);
        acc.z = fmaxf(acc.z, 0.f); acc.w = fmaxf(acc.w, 0.f);
    }
    ushort4 o;
    o.x = f2h(acc.x); o.y = f2h(acc.y); o.z = f2h(acc.z); o.w = f2h(acc.w);
    *(ushort4*)&out[(long)node * 256 + lane * 4] = o;
}

// ---------------- softmax over NC classes, one wave per row ----------------

__global__ __launch_bounds__(256) void k_softmax(
    const float* __restrict__ logits, void* __restrict__ out, int M, int NC,
    const int* __restrict__ dflag)
{
    const int wave = threadIdx.x >> 6;
    const int lane = threadIdx.x & 63;
    const int row = blockIdx.x * 4 + wave;
    if (row >= M) return;
    const bool bf = (*dflag != 0);

    float v = (lane < NC) ? logits[(long)row * NC + lane] : -INFINITY;
    float m = v;
    #pragma unroll
    for (int off = 32; off; off >>= 1) m = fmaxf(m, __shfl_xor(m, off, 64));
    float p = (lane < NC) ? expf(v - m) : 0.f;
    float s = p;
    #pragma unroll
    for (int off = 32; off; off >>= 1) s += __shfl_xor(s, off, 64);
    if (lane < NC) {
        float r = p / s;
        if (bf) ((unsigned short*)out)[(long)row * NC + lane] = f2bf(r);
        else    ((float*)out)[(long)row * NC + lane] = r;
    }
}

// ---------------- orchestration ----------------

extern "C" void kernel_launch(void* const* d_in, const int* in_sizes, int n_in,
                              void* d_out, int out_size, void* d_ws, size_t ws_size,
                              hipStream_t stream) {
    const void* x    = d_in[0];
    const int*  esrc = (const int*)d_in[1];
    const int*  edst = (const int*)d_in[2];
    const void* ewin = d_in[3];
    const void* w1 = d_in[4],  *b1 = d_in[5];
    const void* w2 = d_in[6],  *b2 = d_in[7];
    const void* wc1 = d_in[8], *bc1 = d_in[9];
    const void* wc2 = d_in[10], *bc2 = d_in[11];
    const void* wc3 = d_in[12], *bc3 = d_in[13];
    const void* wc4 = d_in[14], *bc4 = d_in[15];

    const int HID  = in_sizes[5];                 // 256
    const int IND  = in_sizes[4] / HID;           // 512
    const int HID2 = in_sizes[9];                 // 512
    const int NC   = in_sizes[15];                // 40
    const int M    = in_sizes[0] / IND;           // 100000
    const int E    = in_sizes[1];                 // 3200000

    char* ws = (char*)d_ws;
    int* dflag = (int*)ws;                                        // 256 B slot
    unsigned short* bufA = (unsigned short*)(ws + 256);           // sup (f16, 51.2 MB used)
    unsigned short* bufB = (unsigned short*)(ws + 256 + 102400000L);  // h1/h2 (f16)
    char*  wsC  = ws + 256 + 204800000L;                          // h3/h5 (f16) / CSR
    char*  wsD  = wsC + 204800000L;                               // h4 (f16)
    unsigned short* bufC = (unsigned short*)wsC;
    unsigned short* bufD = (unsigned short*)wsD;

    // CSR arrays live inside bufC's region (dead before the MLP starts)
    int* counts  = (int*)wsC;
    int* row_ptr = counts + 100352;
    int* cursor  = row_ptr + 100352;
    int* bsums   = cursor + 100352;
    int* ex      = bsums + 1024;
    int* es      = ex + 100352;
    float* ewS   = (float*)(es + E);

    float* logits = (float*)bufA;   // reuse after support2 is dead (16 MB)

    // 0. dtype sniff
    k_detect<<<1, 256, 0, stream>>>((const unsigned int*)x, dflag);

    // 1. CSR build
    hipMemsetAsync(counts, 0, 100352 * sizeof(int), stream);
    hipMemsetAsync(cursor, 0, 100352 * sizeof(int), stream);
    k_hist<<<(E + 255) / 256, 256, 0, stream>>>(edst, E, counts);
    int nb = (M + 1023) / 1024;                                   // 98
    k_scan_a<<<nb, 256, 0, stream>>>(counts, M, ex, bsums);
    k_scan_b<<<1, 256, 0, stream>>>(bsums, nb);
    k_scan_c<<<(M + 255) / 256, 256, 0, stream>>>(ex, bsums, M, E, row_ptr);
    k_scatter<<<(E + 255) / 256, 256, 0, stream>>>(esrc, edst, ewin, dflag, row_ptr, cursor, E, es, ewS);

    const int gm128 = (M + 127) / 128;   // 782
    dim3 blk(256);

    // 2. support1 = x @ w1                      [M,512]@[512,256] -> bufA (f16)
    k_gemm<<<dim3(HID / 128, gm128), blk, 0, stream>>>(x, w1, nullptr, bufA, M, IND, HID, 0, 2, 0, dflag);
    // 3. h1 = relu(spmm(support1) + b1)        -> bufB (f16)
    k_spmm<<<(M + 3) / 4, blk, 0, stream>>>(bufA, es, ewS, row_ptr, b1, bufB, M, 1, dflag);
    // 4. support2 = h1 @ w2                    -> bufA (f16)
    k_gemm<<<dim3(HID / 128, gm128), blk, 0, stream>>>(bufB, w2, nullptr, bufA, M, HID, HID, 2, 2, 0, dflag);
    // 5. h2 = spmm(support2) + b2              -> bufB (f16)
    k_spmm<<<(M + 3) / 4, blk, 0, stream>>>(bufA, es, ewS, row_ptr, b2, bufB, M, 0, dflag);
    // 6. h3 = relu(h2 @ wc1 + bc1)             [M,256]@[256,512] -> bufC (f16, CSR now dead)
    k_gemm<<<dim3(HID2 / 128, gm128), blk, 0, stream>>>(bufB, wc1, bc1, bufC, M, HID, HID2, 2, 2, 1, dflag);
    // 7. h4 = relu(h3 @ wc2 + bc2)             -> bufD (f16)
    k_gemm<<<dim3(HID2 / 128, gm128), blk, 0, stream>>>(bufC, wc2, bc2, bufD, M, HID2, HID2, 2, 2, 1, dflag);
    // 8. h5 = relu(h4 @ wc3 + bc3)             -> bufC (f16)
    k_gemm<<<dim3(HID2 / 128, gm128), blk, 0, stream>>>(bufD, wc3, bc3, bufC, M, HID2, HID2, 2, 2, 1, dflag);
    // 9. logits = h5 @ wc4 + bc4               [M,512]@[512,40] -> bufA (fp32)
    k_gemm<<<dim3(1, gm128), blk, 0, stream>>>(bufC, wc4, bc4, logits, M, HID2, NC, 2, 0, 0, dflag);
    // 10. softmax -> d_out
    k_softmax<<<(M + 3) / 4, blk, 0, stream>>>(logits, d_out, M, NC, dflag);
}

// Round 3
// 2025.656 us; speedup vs baseline: 1.9978x; 1.1860x over previous
//
#include <hip/hip_runtime.h>
#include <math.h>

typedef __attribute__((ext_vector_type(8))) _Float16 f16x8;       // 8 f16 = 4 VGPR (MFMA A/B frag)
typedef __attribute__((ext_vector_type(4))) float f32x4;          // MFMA C/D frag
typedef __attribute__((ext_vector_type(8))) unsigned short ushort8;

// ---------------- dtype helpers ----------------

__device__ __forceinline__ float bf2f(unsigned short u) {
    union { unsigned int i; float f; } x; x.i = ((unsigned int)u) << 16; return x.f;
}
__device__ __forceinline__ unsigned short f2bf(float f) {
    union { float f; unsigned int i; } x; x.f = f;
    unsigned int i = x.i;
    unsigned int r = (i + 0x7FFFu + ((i >> 16) & 1u)) >> 16;   // RNE
    return (unsigned short)r;
}
__device__ __forceinline__ float h2f(unsigned short u) {
    _Float16 h; __builtin_memcpy(&h, &u, 2); return (float)h;
}
__device__ __forceinline__ unsigned short f2h(float f) {
    _Float16 h = (_Float16)f; unsigned short u; __builtin_memcpy(&u, &h, 2); return u;
}
__device__ __forceinline__ float ld1(const void* p, long i, bool bf) {
    return bf ? bf2f(((const unsigned short*)p)[i]) : ((const float*)p)[i];
}
__device__ __forceinline__ float4 ld4(const void* p, long i, bool bf) {
    if (bf) {
        ushort4 u = *(const ushort4*)((const unsigned short*)p + i);
        return make_float4(bf2f(u.x), bf2f(u.y), bf2f(u.z), bf2f(u.w));
    }
    return *(const float4*)((const float*)p + i);
}

// Detect whether float tensors are bf16-packed (see round 0 notes).
__global__ void k_detect(const unsigned int* __restrict__ x, int* __restrict__ flag) {
    int t = threadIdx.x;
    int hits = 0;
    for (int i = 0; i < 64; i++) {
        unsigned int w = x[t * 64 + i];
        unsigned int e = (w >> 7) & 0xFF;
        hits += (e >= 0x70 && e <= 0x85) ? 1 : 0;
    }
    __shared__ int sh[256];
    sh[t] = hits;
    __syncthreads();
    for (int off = 128; off; off >>= 1) {
        if (t < off) sh[t] += sh[t + off];
        __syncthreads();
    }
    if (t == 0) *flag = (sh[0] > 8192) ? 1 : 0;   // 16384 words total
}

// ---------------- CSR build (counting sort by dst) ----------------

__global__ void k_hist(const int* __restrict__ dst, int E, int* __restrict__ counts) {
    int i = blockIdx.x * blockDim.x + threadIdx.x;
    if (i < E) atomicAdd(&counts[dst[i]], 1);
}

__global__ void k_scan_a(const int* __restrict__ counts, int N,
                         int* __restrict__ ex, int* __restrict__ bsums) {
    __shared__ int s[256];
    int t = threadIdx.x;
    int base = blockIdx.x * 1024;
    int v[4]; int sum = 0;
    #pragma unroll
    for (int j = 0; j < 4; j++) {
        int idx = base + t * 4 + j;
        v[j] = (idx < N) ? counts[idx] : 0;
        sum += v[j];
    }
    s[t] = sum;
    __syncthreads();
    for (int off = 1; off < 256; off <<= 1) {
        int x = (t >= off) ? s[t - off] : 0;
        __syncthreads();
        s[t] += x;
        __syncthreads();
    }
    int run = (t > 0) ? s[t - 1] : 0;
    #pragma unroll
    for (int j = 0; j < 4; j++) {
        int idx = base + t * 4 + j;
        if (idx < N) ex[idx] = run;
        run += v[j];
    }
    if (t == 255) bsums[blockIdx.x] = s[255];
}

__global__ void k_scan_b(int* __restrict__ bsums, int nb) {
    __shared__ int s[256];
    int t = threadIdx.x;
    s[t] = (t < nb) ? bsums[t] : 0;
    __syncthreads();
    for (int off = 1; off < 256; off <<= 1) {
        int x = (t >= off) ? s[t - off] : 0;
        __syncthreads();
        s[t] += x;
        __syncthreads();
    }
    if (t < nb) bsums[t] = (t > 0) ? s[t - 1] : 0;
}

__global__ void k_scan_c(const int* __restrict__ ex, const int* __restrict__ bsums,
                         int N, int E, int* __restrict__ row_ptr) {
    int i = blockIdx.x * blockDim.x + threadIdx.x;
    if (i < N) row_ptr[i] = ex[i] + bsums[i >> 10];
    if (i == 0) row_ptr[N] = E;
}

__global__ void k_scatter(const int* __restrict__ src, const int* __restrict__ dst,
                          const void* __restrict__ ewin, const int* __restrict__ dflag,
                          const int* __restrict__ row_ptr, int* __restrict__ cursor,
                          int E, int* __restrict__ es, float* __restrict__ ew) {
    int i = blockIdx.x * blockDim.x + threadIdx.x;
    if (i >= E) return;
    bool bf = (*dflag != 0);
    int d = dst[i];
    int p = row_ptr[d] + atomicAdd(&cursor[d], 1);
    es[p] = src[i];
    ew[p] = ld1(ewin, i, bf);
}

// ---------------- MFMA GEMM: C = act(A[M,K] @ W[K,N] (+ bias)) ----------------
// 128x128 tile, 256 threads (4 waves, 2x2), BK=32, mfma_f32_16x16x32_f16.
// A modes: a_kind=0 -> input tensor (fp32 -> exact f16 hi/lo split, 2 A-passes;
//                      raw-bf16 -> exact f16 convert, 1 pass)
//          a_kind=2 -> fp16 intermediate, raw copy, 1 pass (exact)
// Weights bf16 -> exact f16 convert (8-bit mantissa in 11-bit, small values);
// fp32 weights -> f16 hi/lo split, extra ah*bl pass.

__global__ __launch_bounds__(256) void k_gemm(
    const void* __restrict__ A, const void* __restrict__ W, const void* __restrict__ bias,
    void* __restrict__ C, int M, int K, int N,
    int a_kind, int c_mode, int act, const int* __restrict__ dflag)
{
    const bool inbf = (*dflag != 0);
    const int  a_mode = (a_kind == 2) ? 2 : (inbf ? 1 : 0);   // 0 fp32, 1 bf16 raw, 2 f16
    const bool a_lo = (a_mode == 0);
    const bool b_lo = !inbf;

    // [row][k] f16, k contiguous; pad 32->40 elems keeps 16B alignment and
    // makes the 16-row-strided ds_read_b128 ~2-way (free) instead of 16-way.
    __shared__ _Float16 Ah[128][40];
    __shared__ _Float16 Al[128][40];
    __shared__ _Float16 Bh[128][40];   // B stored transposed: [n][k]
    __shared__ _Float16 Bl[128][40];

    const int t  = threadIdx.x;
    const int m0 = blockIdx.y * 128;        // grid: x = n-tiles (fast) -> A-panel L2 reuse
    const int n0 = blockIdx.x * 128;

    const int lane = t & 63;
    const int wv   = t >> 6;
    const int wm   = (wv & 1) * 64;         // wave's 64x64 quadrant
    const int wn   = (wv >> 1) * 64;
    const int lr   = lane & 15;             // frag row/col
    const int lk   = (lane >> 4) * 8;       // frag k-offset (8 contiguous f16 = b128)

    f32x4 acc[4][4];
    const f32x4 vzero = {0.f, 0.f, 0.f, 0.f};
    #pragma unroll
    for (int i = 0; i < 4; i++)
        #pragma unroll
        for (int j = 0; j < 4; j++) acc[i][j] = vzero;

    // A staging: thread -> (row = t>>1, k-half = (t&1)*16), 16 elems = 2x 8 per plane
    const int  ar  = t >> 1;
    const int  ak  = (t & 1) * 16;
    const long agm = (long)(m0 + ar);

    // B staging: thread -> (n-quad = t&31, k-quad-group = t>>5), transpose into LDS
    const int nq = t & 31;
    const int kq = t >> 5;
    const int gn = n0 + nq * 4;

    for (int k0 = 0; k0 < K; k0 += 32) {
        // ---- stage A tile (128 x 32) ----
        #pragma unroll
        for (int c = 0; c < 2; c++) {
            long base = agm * K + k0 + ak + c * 8;
            if (a_mode == 2) {
                uint4 raw = make_uint4(0, 0, 0, 0);
                if (agm < M) raw = *(const uint4*)((const unsigned short*)A + base);
                *(uint4*)&Ah[ar][ak + c * 8] = raw;
            } else if (a_mode == 1) {
                union { unsigned short u[8]; uint4 q; } r;
                r.q = make_uint4(0, 0, 0, 0);
                if (agm < M) r.q = *(const uint4*)((const unsigned short*)A + base);
                union { _Float16 h[8]; uint4 q; } H;
                #pragma unroll
                for (int e = 0; e < 8; e++) H.h[e] = (_Float16)bf2f(r.u[e]);
                *(uint4*)&Ah[ar][ak + c * 8] = H.q;
            } else {
                float4 v0 = make_float4(0.f, 0.f, 0.f, 0.f), v1 = v0;
                if (agm < M) {
                    v0 = *(const float4*)((const float*)A + base);
                    v1 = *(const float4*)((const float*)A + base + 4);
                }
                float f[8] = {v0.x, v0.y, v0.z, v0.w, v1.x, v1.y, v1.z, v1.w};
                union { _Float16 h[8]; uint4 q; } H, L;
                #pragma unroll
                for (int e = 0; e < 8; e++) {
                    _Float16 hh = (_Float16)f[e];
                    H.h[e] = hh;
                    L.h[e] = (_Float16)(f[e] - (float)hh);
                }
                *(uint4*)&Ah[ar][ak + c * 8] = H.q;
                *(uint4*)&Al[ar][ak + c * 8] = L.q;
            }
        }
        // ---- stage B tile (32 x 128), transposed to [n][k] ----
        {
            float w[4][4];   // [k-off][n-off]
            #pragma unroll
            for (int i = 0; i < 4; i++) {
                float4 v = make_float4(0.f, 0.f, 0.f, 0.f);
                if (gn < N) v = ld4(W, (long)(k0 + kq * 4 + i) * N + gn, inbf);
                w[i][0] = v.x; w[i][1] = v.y; w[i][2] = v.z; w[i][3] = v.w;
            }
            #pragma unroll
            for (int j = 0; j < 4; j++) {
                union { _Float16 h[4]; uint2 q; } H, L;
                #pragma unroll
                for (int i = 0; i < 4; i++) {
                    _Float16 hh = (_Float16)w[i][j];
                    H.h[i] = hh;
                    if (b_lo) L.h[i] = (_Float16)(w[i][j] - (float)hh);
                }
                *(uint2*)&Bh[nq * 4 + j][kq * 4] = H.q;
                if (b_lo) *(uint2*)&Bl[nq * 4 + j][kq * 4] = L.q;
            }
        }
        __syncthreads();

        // ---- MFMA: hi*hi (+ lo*hi) (+ hi*lo) ----
        f16x8 ah[4], bh[4];
        #pragma unroll
        for (int f = 0; f < 4; f++) {
            ah[f] = *(const f16x8*)&Ah[wm + f * 16 + lr][lk];
            bh[f] = *(const f16x8*)&Bh[wn + f * 16 + lr][lk];
        }
        #pragma unroll
        for (int i = 0; i < 4; i++)
            #pragma unroll
            for (int j = 0; j < 4; j++)
                acc[i][j] = __builtin_amdgcn_mfma_f32_16x16x32_f16(ah[i], bh[j], acc[i][j], 0, 0, 0);
        if (a_lo) {
            f16x8 al[4];
            #pragma unroll
            for (int f = 0; f < 4; f++) al[f] = *(const f16x8*)&Al[wm + f * 16 + lr][lk];
            #pragma unroll
            for (int i = 0; i < 4; i++)
                #pragma unroll
                for (int j = 0; j < 4; j++)
                    acc[i][j] = __builtin_amdgcn_mfma_f32_16x16x32_f16(al[i], bh[j], acc[i][j], 0, 0, 0);
        }
        if (b_lo) {
            f16x8 bl[4];
            #pragma unroll
            for (int f = 0; f < 4; f++) bl[f] = *(const f16x8*)&Bl[wn + f * 16 + lr][lk];
            #pragma unroll
            for (int i = 0; i < 4; i++)
                #pragma unroll
                for (int j = 0; j < 4; j++)
                    acc[i][j] = __builtin_amdgcn_mfma_f32_16x16x32_f16(ah[i], bl[j], acc[i][j], 0, 0, 0);
        }
        __syncthreads();
    }

    // ---- epilogue: C/D layout col=lane&15, row=(lane>>4)*4+reg [m89-verified] ----
    const bool has_bias = (bias != nullptr);
    const int  rbase = (lane >> 4) * 4;
    #pragma unroll
    for (int j = 0; j < 4; j++) {
        int col = n0 + wn + j * 16 + lr;
        if (col >= N) continue;
        float bv = has_bias ? ld1(bias, col, inbf) : 0.f;
        #pragma unroll
        for (int i = 0; i < 4; i++) {
            #pragma unroll
            for (int r = 0; r < 4; r++) {
                int row = m0 + wm + i * 16 + rbase + r;
                if (row < M) {
                    float v = acc[i][j][r] + bv;
                    if (act) v = fmaxf(v, 0.f);
                    if (c_mode == 2) ((unsigned short*)C)[(long)row * N + col] = f2h(v);
                    else             ((float*)C)[(long)row * N + col] = v;
                }
            }
        }
    }
}

// ---------------- SPMM: out[d] = act(sum_e w[e]*sup[src[e]] + bias), F=256 ----------------
// One wave per dst node. Wave split into two 32-lane halves, each half owns a
// DIFFERENT edge per iteration; lane (l&31) owns 8 feats (16B ushort8 load).
// -> 2x bytes/instr + 2x fewer iters + unroll(4) = ~8 gathers in flight/wave
// (old version: ~2). Halves combined at the end via one shfl_xor(32) pass.

__global__ __launch_bounds__(256) void k_spmm(
    const unsigned short* __restrict__ sup, const int* __restrict__ es,
    const float* __restrict__ ew, const int* __restrict__ row_ptr,
    const void* __restrict__ bias, unsigned short* __restrict__ out,
    int Nn, int act, const int* __restrict__ dflag)
{
    const int wave = threadIdx.x >> 6;
    const int lane = threadIdx.x & 63;
    const int node = blockIdx.x * 4 + wave;
    if (node >= Nn) return;
    const bool bf = (*dflag != 0);

    const int half = lane >> 5;          // 0 or 1
    const int fl   = (lane & 31) * 8;    // feature base (8 f16 = 16 B)

    const int e0 = row_ptr[node], e1 = row_ptr[node + 1];
    float acc[8] = {};

    #pragma unroll 4
    for (int e = e0 + half; e < e1; e += 2) {
        int s = es[e];
        float w = ew[e];
        ushort8 u = *(const ushort8*)&sup[(long)s * 256 + fl];
        #pragma unroll
        for (int i = 0; i < 8; i++) acc[i] += w * h2f(u[i]);
    }

    // combine the two half-wave partial sums (lane l <-> lane l+32)
    #pragma unroll
    for (int i = 0; i < 8; i++) acc[i] += __shfl_xor(acc[i], 32, 64);

    if (half == 0) {
        float4 b0 = ld4(bias, fl, bf);
        float4 b1 = ld4(bias, fl + 4, bf);
        float bb[8] = {b0.x, b0.y, b0.z, b0.w, b1.x, b1.y, b1.z, b1.w};
        ushort8 o;
        #pragma unroll
        for (int i = 0; i < 8; i++) {
            float v = acc[i] + bb[i];
            if (act) v = fmaxf(v, 0.f);
            o[i] = f2h(v);
        }
        *(ushort8*)&out[(long)node * 256 + fl] = o;
    }
}

// ---------------- softmax over NC classes, one wave per row ----------------

__global__ __launch_bounds__(256) void k_softmax(
    const float* __restrict__ logits, void* __restrict__ out, int M, int NC,
    const int* __restrict__ dflag)
{
    const int wave = threadIdx.x >> 6;
    const int lane = threadIdx.x & 63;
    const int row = blockIdx.x * 4 + wave;
    if (row >= M) return;
    const bool bf = (*dflag != 0);

    float v = (lane < NC) ? logits[(long)row * NC + lane] : -INFINITY;
    float m = v;
    #pragma unroll
    for (int off = 32; off; off >>= 1) m = fmaxf(m, __shfl_xor(m, off, 64));
    float p = (lane < NC) ? expf(v - m) : 0.f;
    float s = p;
    #pragma unroll
    for (int off = 32; off; off >>= 1) s += __shfl_xor(s, off, 64);
    if (lane < NC) {
        float r = p / s;
        if (bf) ((unsigned short*)out)[(long)row * NC + lane] = f2bf(r);
        else    ((float*)out)[(long)row * NC + lane] = r;
    }
}

// ---------------- orchestration ----------------

extern "C" void kernel_launch(void* const* d_in, const int* in_sizes, int n_in,
                              void* d_out, int out_size, void* d_ws, size_t ws_size,
                              hipStream_t stream) {
    const void* x    = d_in[0];
    const int*  esrc = (const int*)d_in[1];
    const int*  edst = (const int*)d_in[2];
    const void* ewin = d_in[3];
    const void* w1 = d_in[4],  *b1 = d_in[5];
    const void* w2 = d_in[6],  *b2 = d_in[7];
    const void* wc1 = d_in[8], *bc1 = d_in[9];
    const void* wc2 = d_in[10], *bc2 = d_in[11];
    const void* wc3 = d_in[12], *bc3 = d_in[13];
    const void* wc4 = d_in[14], *bc4 = d_in[15];

    const int HID  = in_sizes[5];                 // 256
    const int IND  = in_sizes[4] / HID;           // 512
    const int HID2 = in_sizes[9];                 // 512
    const int NC   = in_sizes[15];                // 40
    const int M    = in_sizes[0] / IND;           // 100000
    const int E    = in_sizes[1];                 // 3200000

    char* ws = (char*)d_ws;
    int* dflag = (int*)ws;                                        // 256 B slot
    unsigned short* bufA = (unsigned short*)(ws + 256);           // sup (f16, 51.2 MB used)
    unsigned short* bufB = (unsigned short*)(ws + 256 + 102400000L);  // h1/h2 (f16)
    char*  wsC  = ws + 256 + 204800000L;                          // h3/h5 (f16) / CSR
    char*  wsD  = wsC + 204800000L;                               // h4 (f16)
    unsigned short* bufC = (unsigned short*)wsC;
    unsigned short* bufD = (unsigned short*)wsD;

    // CSR arrays live inside bufC's region (dead before the MLP starts)
    int* counts  = (int*)wsC;
    int* row_ptr = counts + 100352;
    int* cursor  = row_ptr + 100352;
    int* bsums   = cursor + 100352;
    int* ex      = bsums + 1024;
    int* es      = ex + 100352;
    float* ewS   = (float*)(es + E);

    float* logits = (float*)bufA;   // reuse after support2 is dead (16 MB)

    // 0. dtype sniff
    k_detect<<<1, 256, 0, stream>>>((const unsigned int*)x, dflag);

    // 1. CSR build
    hipMemsetAsync(counts, 0, 100352 * sizeof(int), stream);
    hipMemsetAsync(cursor, 0, 100352 * sizeof(int), stream);
    k_hist<<<(E + 255) / 256, 256, 0, stream>>>(edst, E, counts);
    int nb = (M + 1023) / 1024;                                   // 98
    k_scan_a<<<nb, 256, 0, stream>>>(counts, M, ex, bsums);
    k_scan_b<<<1, 256, 0, stream>>>(bsums, nb);
    k_scan_c<<<(M + 255) / 256, 256, 0, stream>>>(ex, bsums, M, E, row_ptr);
    k_scatter<<<(E + 255) / 256, 256, 0, stream>>>(esrc, edst, ewin, dflag, row_ptr, cursor, E, es, ewS);

    const int gm128 = (M + 127) / 128;   // 782
    dim3 blk(256);

    // 2. support1 = x @ w1                      [M,512]@[512,256] -> bufA (f16)
    k_gemm<<<dim3(HID / 128, gm128), blk, 0, stream>>>(x, w1, nullptr, bufA, M, IND, HID, 0, 2, 0, dflag);
    // 3. h1 = relu(spmm(support1) + b1)        -> bufB (f16)
    k_spmm<<<(M + 3) / 4, blk, 0, stream>>>(bufA, es, ewS, row_ptr, b1, bufB, M, 1, dflag);
    // 4. support2 = h1 @ w2                    -> bufA (f16)
    k_gemm<<<dim3(HID / 128, gm128), blk, 0, stream>>>(bufB, w2, nullptr, bufA, M, HID, HID, 2, 2, 0, dflag);
    // 5. h2 = spmm(support2) + b2              -> bufB (f16)
    k_spmm<<<(M + 3) / 4, blk, 0, stream>>>(bufA, es, ewS, row_ptr, b2, bufB, M, 0, dflag);
    // 6. h3 = relu(h2 @ wc1 + bc1)             [M,256]@[256,512] -> bufC (f16, CSR now dead)
    k_gemm<<<dim3(HID2 / 128, gm128), blk, 0, stream>>>(bufB, wc1, bc1, bufC, M, HID, HID2, 2, 2, 1, dflag);
    // 7. h4 = relu(h3 @ wc2 + bc2)             -> bufD (f16)
    k_gemm<<<dim3(HID2 / 128, gm128), blk, 0, stream>>>(bufC, wc2, bc2, bufD, M, HID2, HID2, 2, 2, 1, dflag);
    // 8. h5 = relu(h4 @ wc3 + bc3)             -> bufC (f16)
    k_gemm<<<dim3(HID2 / 128, gm128), blk, 0, stream>>>(bufD, wc3, bc3, bufC, M, HID2, HID2, 2, 2, 1, dflag);
    // 9. logits = h5 @ wc4 + bc4               [M,512]@[512,40] -> bufA (fp32)
    k_gemm<<<dim3(1, gm128), blk, 0, stream>>>(bufC, wc4, bc4, logits, M, HID2, NC, 2, 0, 0, dflag);
    // 10. softmax -> d_out
    k_softmax<<<(M + 3) / 4, blk, 0, stream>>>(logits, d_out, M, NC, dflag);
}